// Round 4
// baseline (182.252 us; speedup 1.0000x reference)
//
#include <hip/hip_runtime.h>

#define DEVINL __device__ __forceinline__

// 3-level a-trous B3-spline UWT, fused single kernel.
// Tile: 32x64 output, staged 64x92 rows (2..93), SW padded to 68 floats.
// pack p = tid&15 owns 4 consecutive cols (float4); ty = tid>>4 is the
// 16-lane DPP row-group id. Horizontal conv via DPP row_shr/row_shl.
//
// ROLLING REGISTER WINDOWS: row-groups own contiguous row BANDS so the
// 5-tap vertical window rolls in registers:
//   L0 (D=1): band 6/5, 4 preload + 1 ds_read per row (was 5/row)
//   L1 (D=2): band 5, dual parity chains, 8 preload + 1/row (was 5/row)
//   L2 (D=4): band too short to amortize warm-up -> strided, 5/row, no guard
// LDS b128 ops/thread: ~89 -> ~60. Rolled reads use base+imm offsets.
// LDS ping-pong A<->B, 2 x 96 x 68 x 4 = 52.2 KB -> 3 blocks/CU.

constexpr int W_IMG = 1024;
constexpr int H_IMG = 1024;
constexpr int TX = 32;                    // output cols per tile
constexpr int TY = 64;                    // output rows per tile (GYT exact)
constexpr int HALO = 16;                  // >= 2*(1+2+4)=14
constexpr int SW = 68;                    // LDS row STRIDE in floats (64 + 4 pad)
constexpr int SH = TY + 2 * HALO;         // 96 row slots (2..93 staged)
constexpr int GXT = W_IMG / TX;           // 32
constexpr int GYT = H_IMG / TY;           // 16 (exact)

constexpr float TP0 = 1.0f / 16.0f;
constexpr float TP1 = 1.0f / 4.0f;
constexpr float TP2 = 3.0f / 8.0f;

typedef float f32x4 __attribute__((ext_vector_type(4)));

// DPP cross-lane fetch within 16-lane rows. row_shr:n (0x110|n) = value from
// lane i-n; row_shl:n (0x100|n) = value from lane i+n. bound_ctrl=1 -> 0 at
// row edges. Corrupt columns from edge-zeros stay confined: L0 corrupts
// staged cols {0,1},{62,63}; L1 extends to {0..5},{58..63}; L2 to
// {0..13},{50..63}. Valid outputs use staged cols 16..47 -> 2-col margin.
template <int CTRL>
DEVINL float dppf(float x) {
    return __int_as_float(__builtin_amdgcn_update_dpp(
        0, __float_as_int(x), CTRL, 0xF, 0xF, true));
}

DEVINL int reflx(int g) {
    g = g < 0 ? -g : g;
    return g >= W_IMG ? 2 * W_IMG - 2 - g : g;
}

DEVINL void nt_store4(float* p, float a, float b, float c, float d) {
    f32x4 t;
    t.x = a; t.y = b; t.z = c; t.w = d;
    __builtin_nontemporal_store(t, (f32x4*)p);
}

DEVINL float4 vert(const float4& a0, const float4& a1, const float4& a2,
                   const float4& a3, const float4& a4) {
    float4 v;
    v.x = TP0 * (a0.x + a4.x) + TP1 * (a1.x + a3.x) + TP2 * a2.x;
    v.y = TP0 * (a0.y + a4.y) + TP1 * (a1.y + a3.y) + TP2 * a2.y;
    v.z = TP0 * (a0.z + a4.z) + TP1 * (a1.z + a3.z) + TP2 * a2.z;
    v.w = TP0 * (a0.w + a4.w) + TP1 * (a1.w + a3.w) + TP2 * a2.w;
    return v;
}

template <int D>
DEVINL float4 horiz(const float4& v) {
    float4 u;
    if constexpr (D == 1) {
        const float am2 = dppf<0x111>(v.z);  // col-2 for comp0
        const float am1 = dppf<0x111>(v.w);  // col-1 for comp0
        const float ap1 = dppf<0x101>(v.x);  // col+1 for comp3
        const float ap2 = dppf<0x101>(v.y);  // col+2 for comp3
        u.x = TP0 * (am2 + v.z) + TP1 * (am1 + v.y) + TP2 * v.x;
        u.y = TP0 * (am1 + v.w) + TP1 * (v.x + v.z) + TP2 * v.y;
        u.z = TP0 * (v.x + ap1) + TP1 * (v.y + v.w) + TP2 * v.z;
        u.w = TP0 * (v.y + ap2) + TP1 * (v.z + ap1) + TP2 * v.w;
    } else if constexpr (D == 2) {
        u.x = TP0 * (dppf<0x111>(v.x) + dppf<0x101>(v.x)) +
              TP1 * (dppf<0x111>(v.z) + v.z) + TP2 * v.x;
        u.y = TP0 * (dppf<0x111>(v.y) + dppf<0x101>(v.y)) +
              TP1 * (dppf<0x111>(v.w) + v.w) + TP2 * v.y;
        u.z = TP0 * (dppf<0x111>(v.z) + dppf<0x101>(v.z)) +
              TP1 * (v.x + dppf<0x101>(v.x)) + TP2 * v.z;
        u.w = TP0 * (dppf<0x111>(v.w) + dppf<0x101>(v.w)) +
              TP1 * (v.y + dppf<0x101>(v.y)) + TP2 * v.w;
    } else {  // D == 4: same component, packs +/-1 and +/-2
        u.x = TP0 * (dppf<0x112>(v.x) + dppf<0x102>(v.x)) +
              TP1 * (dppf<0x111>(v.x) + dppf<0x101>(v.x)) + TP2 * v.x;
        u.y = TP0 * (dppf<0x112>(v.y) + dppf<0x102>(v.y)) +
              TP1 * (dppf<0x111>(v.y) + dppf<0x101>(v.y)) + TP2 * v.y;
        u.z = TP0 * (dppf<0x112>(v.z) + dppf<0x102>(v.z)) +
              TP1 * (dppf<0x111>(v.z) + dppf<0x101>(v.z)) + TP2 * v.z;
        u.w = TP0 * (dppf<0x112>(v.w) + dppf<0x102>(v.w)) +
              TP1 * (dppf<0x111>(v.w) + dppf<0x101>(v.w)) + TP2 * v.w;
    }
    return u;
}

// store w_LVL = center - u (and optionally c_3 = u) for output rows/cols
template <int LVL, bool ALSO_C>
DEVINL void maybe_store(float* __restrict__ out, int b4, int oy0, int gx0,
                        int p, int r, const float4& center, const float4& u) {
    const int ly = r - HALO;
    if ((unsigned)ly < (unsigned)TY && p >= 4 && p < 12) {
        const int oy = oy0 + ly;
        const int ox = gx0 + p * 4 - HALO;
        const size_t base = ((size_t)(b4 + LVL) * H_IMG + oy) * W_IMG + ox;
        nt_store4(&out[base], center.x - u.x, center.y - u.y, center.z - u.z,
                  center.w - u.w);
        if constexpr (ALSO_C) {
            const size_t base3 = ((size_t)(b4 + 3) * H_IMG + oy) * W_IMG + ox;
            nt_store4(&out[base3], u.x, u.y, u.z, u.w);
        }
    }
}

// L0 (D=1): rolling 5-row window. Bands: ty<8 -> 6 rows from 4+6*ty,
// ty>=8 -> 5 rows from 52+5*(ty-8). Output rows 4..91 exactly.
DEVINL void level0(const float* src, float* dst, float* __restrict__ out,
                   int b4, int oy0, int gx0, int p, int ty) {
    const int c4 = p * 4;
    const int r0 = ty < 8 ? 4 + 6 * ty : 52 + 5 * (ty - 8);
    const int band = ty < 8 ? 6 : 5;
    const float* base = &src[r0 * SW + c4];
    float4 w0 = *(const float4*)(base - 2 * SW);
    float4 w1 = *(const float4*)(base - 1 * SW);
    float4 w2 = *(const float4*)(base);
    float4 w3 = *(const float4*)(base + 1 * SW);
#pragma unroll
    for (int k = 0; k < 6; ++k) {
        if (k < band) {
            const float4 w4 = *(const float4*)(base + (k + 2) * SW);
            const float4 v = vert(w0, w1, w2, w3, w4);
            const float4 u = horiz<1>(v);
            maybe_store<0, false>(out, b4, oy0, gx0, p, r0 + k, w2, u);
            *(float4*)&dst[(r0 + k) * SW + c4] = u;
            w0 = w1; w1 = w2; w2 = w3; w3 = w4;
        }
    }
}

// one D=2 rolling step: q0..q3 hold rows r-4,r-2,r,r+2 (same parity as r)
DEVINL void step_d2(const float* base, int off, float4& q0, float4& q1,
                    float4& q2, float4& q3, float* dst,
                    float* __restrict__ out, int b4, int oy0, int gx0, int p,
                    int r) {
    const float4 q4 = *(const float4*)(base + off * SW);
    const float4 v = vert(q0, q1, q2, q3, q4);
    const float4 u = horiz<2>(v);
    maybe_store<1, false>(out, b4, oy0, gx0, p, r, q2, u);
    *(float4*)&dst[r * SW + p * 4] = u;
    q0 = q1; q1 = q2; q2 = q3; q3 = q4;
}

// L1 (D=2): band 5 from r0 = 8+5*ty (rows 8..87 exactly), dual parity chains.
DEVINL void level1(const float* src, float* dst, float* __restrict__ out,
                   int b4, int oy0, int gx0, int p, int ty) {
    const int c4 = p * 4;
    const int r0 = 8 + 5 * ty;
    const float* base = &src[r0 * SW + c4];
    float4 a0 = *(const float4*)(base - 4 * SW);  // parity of r0
    float4 a1 = *(const float4*)(base - 2 * SW);
    float4 a2 = *(const float4*)(base);
    float4 a3 = *(const float4*)(base + 2 * SW);
    float4 b0 = *(const float4*)(base - 3 * SW);  // parity of r0+1
    float4 b1 = *(const float4*)(base - 1 * SW);
    float4 b2 = *(const float4*)(base + 1 * SW);
    float4 b3 = *(const float4*)(base + 3 * SW);
    step_d2(base, 4, a0, a1, a2, a3, dst, out, b4, oy0, gx0, p, r0);
    step_d2(base, 5, b0, b1, b2, b3, dst, out, b4, oy0, gx0, p, r0 + 1);
    step_d2(base, 6, a0, a1, a2, a3, dst, out, b4, oy0, gx0, p, r0 + 2);
    step_d2(base, 7, b0, b1, b2, b3, dst, out, b4, oy0, gx0, p, r0 + 3);
    step_d2(base, 8, a0, a1, a2, a3, dst, out, b4, oy0, gx0, p, r0 + 4);
}

// L2 (D=4): strided (band too short for rolling), rows 16..79 exact -> no
// row guard at all. Writes w_2 and c_3 to global only.
DEVINL void level2(const float* src, float* __restrict__ out, int b4, int oy0,
                   int gx0, int p, int ty) {
    const int c4 = p * 4;
#pragma unroll
    for (int k = 0; k < 4; ++k) {
        const int r = 16 + ty + 16 * k;
        const float4 a0 = *(const float4*)&src[(r - 8) * SW + c4];
        const float4 a1 = *(const float4*)&src[(r - 4) * SW + c4];
        const float4 a2 = *(const float4*)&src[r * SW + c4];
        const float4 a3 = *(const float4*)&src[(r + 4) * SW + c4];
        const float4 a4 = *(const float4*)&src[(r + 8) * SW + c4];
        const float4 v = vert(a0, a1, a2, a3, a4);
        const float4 u = horiz<4>(v);
        if (p >= 4 && p < 12) {  // ly always in [0,TY)
            const int oy = oy0 + r - HALO;
            const int ox = gx0 + c4 - HALO;
            const size_t base = ((size_t)(b4 + 2) * H_IMG + oy) * W_IMG + ox;
            nt_store4(&out[base], a2.x - u.x, a2.y - u.y, a2.z - u.z,
                      a2.w - u.w);
            const size_t base3 = ((size_t)(b4 + 3) * H_IMG + oy) * W_IMG + ox;
            nt_store4(&out[base3], u.x, u.y, u.z, u.w);
        }
    }
}

__global__ __launch_bounds__(256, 3) void uwt3(const float* __restrict__ x,
                                               float* __restrict__ out) {
    __shared__ __align__(16) float A[SH * SW];  // 26112 B
    __shared__ __align__(16) float B[SH * SW];  // total 52224 B -> 3 blk/CU

    const int tid = threadIdx.x;
    const int p = tid & 15;
    const int ty = tid >> 4;
    int bid = blockIdx.x;
    const int bx = bid & 31;  bid >>= 5;      // GXT = 32 (pow2)
    const int by = bid & 15;                  // GYT = 16 (pow2)
    const int b = bid >> 4;
    const int oy0 = by * TY;
    const int gx0 = bx * TX;
    const float* xb = x + (size_t)b * (H_IMG * W_IMG);
    const int c4 = p * 4;
    const bool edge = (bx == 0) || (bx == GXT - 1);

    // stage rows 2..93 only (L0's exact tap reach); 92 rows
#pragma unroll
    for (int k = 0; k < 6; ++k) {
        const int sr = 2 + ty + 16 * k;
        if (sr < 94) {
            int gy = oy0 - HALO + sr;
            gy = gy < 0 ? -gy : gy;
            if (gy >= H_IMG) gy = 2 * H_IMG - 2 - gy;
            const float* row = xb + (size_t)gy * W_IMG;
            const int gx = gx0 - HALO + c4;
            float4 v;
            if (!edge) {
                v = *(const float4*)(row + gx);
            } else {
                v.x = row[reflx(gx)];
                v.y = row[reflx(gx + 1)];
                v.z = row[reflx(gx + 2)];
                v.w = row[reflx(gx + 3)];
            }
            *(float4*)&A[sr * SW + c4] = v;
        }
    }
    __syncthreads();

    level0(A, B, out, b * 4, oy0, gx0, p, ty);  // B rows 4..91
    __syncthreads();
    level1(B, A, out, b * 4, oy0, gx0, p, ty);  // A rows 8..87
    __syncthreads();
    level2(A, out, b * 4, oy0, gx0, p, ty);
}

extern "C" void kernel_launch(void* const* d_in, const int* in_sizes, int n_in,
                              void* d_out, int out_size, void* d_ws,
                              size_t ws_size, hipStream_t stream) {
    const float* x = (const float*)d_in[0];
    float* out = (float*)d_out;
    const int nb = in_sizes[0] / (H_IMG * W_IMG);  // 8
    dim3 grid(nb * GYT * GXT);                     // 8*16*32 = 4096
    uwt3<<<grid, 256, 0, stream>>>(x, out);
}